// Round 1
// baseline (330.069 us; speedup 1.0000x reference)
//
#include <hip/hip_runtime.h>
#include <stdint.h>

// Problem constants
#define S_DIM 512
#define B_DIM 64
#define T_DIM 768
#define A_DIM 512
#define H1_DIM 768
#define H2_DIM 640
#define N_REAL 1408                // 768 + 640 real hidden cols
#define NPAD   1536                // padded to 6 x 256 GEMM n-tiles
#define M_DIM  (S_DIM * B_DIM)     // 32768 rows
#define K_DIM  T_DIM               // 768
#define NSLOT  24                  // 24 n-slots of 64 (slots 22,23 are zero pad)

typedef short s16x8 __attribute__((ext_vector_type(8)));
typedef float f32x4 __attribute__((ext_vector_type(4)));

__device__ __forceinline__ unsigned short f2bf(float f) {
    unsigned u = __float_as_uint(f);
    u += 0x7fffu + ((u >> 16) & 1u);   // round-to-nearest-even
    return (unsigned short)(u >> 16);
}

// --- fused prep: bias GEMV | convW (LDS transpose) | convA (fp32->bf16) ---
#define BIAS_BLKS  (24 * B_DIM)                      // 1536 (chunks 22,23 = pad zero)
#define CONVW_BLKS (24 * 12)                         // 288 (64x64 tiles; nt 22,23 = pad zero)
#define CONVA_BLKS (M_DIM * K_DIM / 4 / 1024)        // 6144

__global__ __launch_bounds__(256) void prep_kernel(const float* __restrict__ ts,
                                                   const float* __restrict__ text,
                                                   const float* __restrict__ anp,
                                                   const float* __restrict__ W11,
                                                   const float* __restrict__ b11,
                                                   const float* __restrict__ W12,
                                                   const float* __restrict__ b12,
                                                   unsigned short* __restrict__ Abf,
                                                   unsigned short* __restrict__ Bt,
                                                   float* __restrict__ cbias) {
    const int blk = blockIdx.x;
    __shared__ float lds[64 * 65];         // transpose tile / bias reduce
    if (blk < BIAS_BLKS) {
        // bias: c[b][n] = x_b @ Wcol_n + bias_n, k-parallel tiled GEMV.
        const int chunk = blk % 24;                        // W-chunk fast: L2 reuse
        const int b     = blk / 24;
        if (chunk >= 22) {                                 // pad cols: zero
            if (threadIdx.x < 64)
                cbias[b * NPAD + N_REAL + (chunk - 22) * 64 + threadIdx.x] = 0.f;
            return;
        }
        const int nl    = threadIdx.x & 63;
        const int kg    = threadIdx.x >> 6;
        float a0 = 0.f, a1 = 0.f;
        if (chunk < 12) {                        // h1: x=text (K=768)
            const int n = chunk * 64 + nl;
            const float* w = W11 + (size_t)T_DIM * H1_DIM + n;
            const float* x = text + b * T_DIM;
            for (int k = kg; k < T_DIM; k += 8) {
                a0 = fmaf(x[k],     w[(size_t)k * H1_DIM],       a0);
                a1 = fmaf(x[k + 4], w[(size_t)(k + 4) * H1_DIM], a1);
            }
        } else {                                 // h2: x=anp (K=512)
            const int n2 = (chunk - 12) * 64 + nl;
            const float* w = W12 + (size_t)T_DIM * H2_DIM + n2;
            const float* x = anp + b * A_DIM;
            for (int k = kg; k < A_DIM; k += 8) {
                a0 = fmaf(x[k],     w[(size_t)k * H2_DIM],       a0);
                a1 = fmaf(x[k + 4], w[(size_t)(k + 4) * H2_DIM], a1);
            }
        }
        lds[kg * 64 + nl] = a0 + a1;
        __syncthreads();
        if (kg == 0) {
            const int n = chunk < 12 ? chunk * 64 + nl : H1_DIM + (chunk - 12) * 64 + nl;
            float base = (chunk < 12) ? b11[n] : b12[n - H1_DIM];
            cbias[b * NPAD + n] =
                base + ((lds[nl] + lds[64 + nl]) + (lds[128 + nl] + lds[192 + nl]));
        }
    } else if (blk < BIAS_BLKS + CONVW_BLKS) {
        // convW: Bt[n][k] = bf16(W[k][n]) via 64x64 LDS transpose tile.
        const int t  = blk - BIAS_BLKS;
        const int nt = t / 12, kt = t % 12;          // n-tile 0..23, k-tile 0..11
        const int n0 = nt * 64, k0 = kt * 64;
        const int lo = threadIdx.x & 63;             // fast index
        const int hi = threadIdx.x >> 6;             // 0..3
        if (nt >= 22) {                              // pad rows: zero
            #pragma unroll
            for (int r = 0; r < 16; ++r)
                Bt[(size_t)(n0 + hi * 16 + r) * K_DIM + k0 + lo] = 0;
            return;
        }
        const float* Wp;  int ld;
        if (nt < 12) { Wp = W11 + n0;            ld = H1_DIM; }
        else         { Wp = W12 + (n0 - H1_DIM); ld = H2_DIM; }
        #pragma unroll
        for (int r = 0; r < 16; ++r) {
            int kl = hi * 16 + r;
            lds[kl * 65 + lo] = Wp[(size_t)(k0 + kl) * ld + lo];
        }
        __syncthreads();
        #pragma unroll
        for (int r = 0; r < 16; ++r) {
            int nl = hi * 16 + r;
            Bt[(size_t)(n0 + nl) * K_DIM + k0 + lo] = f2bf(lds[lo * 65 + nl]);
        }
    } else {
        // convA: text_seq fp32 -> bf16, 4 independent float4 loads per thread
        int i0 = (blk - BIAS_BLKS - CONVW_BLKS) * 1024 + threadIdx.x;
        float4 v0 = ((const float4*)ts)[i0];
        float4 v1 = ((const float4*)ts)[i0 + 256];
        float4 v2 = ((const float4*)ts)[i0 + 512];
        float4 v3 = ((const float4*)ts)[i0 + 768];
        ushort4 o0, o1, o2, o3;
        o0.x = f2bf(v0.x); o0.y = f2bf(v0.y); o0.z = f2bf(v0.z); o0.w = f2bf(v0.w);
        o1.x = f2bf(v1.x); o1.y = f2bf(v1.y); o1.z = f2bf(v1.z); o1.w = f2bf(v1.w);
        o2.x = f2bf(v2.x); o2.y = f2bf(v2.y); o2.z = f2bf(v2.z); o2.w = f2bf(v2.w);
        o3.x = f2bf(v3.x); o3.y = f2bf(v3.y); o3.z = f2bf(v3.z); o3.w = f2bf(v3.w);
        ((ushort4*)Abf)[i0]       = o0;
        ((ushort4*)Abf)[i0 + 256] = o1;
        ((ushort4*)Abf)[i0 + 512] = o2;
        ((ushort4*)Abf)[i0 + 768] = o3;
    }
}

// --- main: 256x256 8-wave MFMA GEMM, 4-phase/K-tile schedule, counted vmcnt ---
// LDS (160 KiB): A ring 3 x 32 KB (tiles t,t+1,t+2) + B dbuf 2 x 32 KB.
// Per tile t (A-buf a=t%3, B-buf p=t&1), phases = (mh,ks) quadrants:
//  p1: ds A-half0/ks0 + B/ks0 ; issue stage B(t+1)        ; bar; 16 MFMA; bar
//  p2: ds A-half1/ks0 (B reuse); issue stage A(t+2)        ; bar; 16 MFMA; bar
//  p3: ds A-half0/ks1 + B/ks1 ;                            ; bar; 16 MFMA; bar
//  p4: ds A-half1/ks1 (B reuse); s_waitcnt vmcnt(4)        ; bar; 16 MFMA; bar
// vmcnt(4): FIFO at p4 = [A(t+1):4, B(t+1):4, A(t+2):4] -> retires everything
// tile t+1 needs, leaves A(t+2) in flight (~6 phases to cover HBM latency).
// Chunk swizzle (c ^ row&7) identical to verified 128^2 kernel: staged via
// pre-swizzled global source, readers XOR with col&7.  XCD swizzle: 768%8==0.
#define BM 256
#define BN 256
#define BK 64
#define GEMM_LDS 163840

#define BARX()  __builtin_amdgcn_s_barrier()
#define VMC4()  asm volatile("s_waitcnt vmcnt(4)" ::: "memory")
#define VMC0()  asm volatile("s_waitcnt vmcnt(0)" ::: "memory")

__global__ __launch_bounds__(512, 2) void gemm_score_kernel(
        const unsigned short* __restrict__ A,    // (M,K) bf16
        const unsigned short* __restrict__ Bt,   // (NPAD,K) bf16
        const float* __restrict__ cbias,         // (B,NPAD)
        const float* __restrict__ W21,           // (768)
        const float* __restrict__ W22,           // (640)
        float* __restrict__ part) {              // [24][M], one writer per element
    extern __shared__ __align__(16) char smem[];
    unsigned short* lds16 = (unsigned short*)smem;

    const int tid  = threadIdx.x;
    const int lb   = blockIdx.x;
    const int gid  = (lb & 7) * 96 + (lb >> 3);  // bijective XCD swizzle (768%8==0)
    const int mt   = gid / 6;                    // 0..127
    const int nt   = gid % 6;                    // 0..5 (n fast: A panel L2 reuse)
    const int m0   = mt * BM;
    const int n0   = nt * BN;
    const int lane = tid & 63;
    const int wave = tid >> 6;                   // 0..7
    const int wm   = wave & 1;                   // 2-way m interleave (16-row)
    const int wn   = wave >> 1;                  // 0..3: wave's 64-col slot
    const int quad = lane >> 4;
    const int col  = lane & 15;

    // staging geometry: gload i covers 64 rows x 64 k; 8 rows/wave, 16B/lane
    const int srow = tid >> 3;                          // 0..63
    const int sko  = ((tid & 7) ^ (srow & 7)) * 8;      // swizzled source chunk
    const unsigned short* gA = A  + (size_t)(m0 + srow) * K_DIM + sko;
    const unsigned short* gB = Bt + (size_t)(n0 + srow) * K_DIM + sko;
    const int ldsw = wave * 1024;

    // fragment-read geometry (A rows interleaved: half*128 + ii*32 + wm*16 + col)
    int arow[4], brow[4];
    #pragma unroll
    for (int ii = 0; ii < 4; ++ii) arow[ii] = (ii * 32 + wm * 16 + col) * BK;
    #pragma unroll
    for (int j = 0; j < 4; ++j)  brow[j] = (wn * 64 + j * 16 + col) * BK;
    const int c0 = (quad ^ (col & 7)) * 8;         // stored chunk, kstep 0
    const int c1 = ((4 + quad) ^ (col & 7)) * 8;   // stored chunk, kstep 1

    f32x4 acc[8][4] = {};

    auto stageA = [&](int buf, int kt) {
        #pragma unroll
        for (int h = 0; h < 2; ++h)
            #pragma unroll
            for (int i = 0; i < 2; ++i)
                __builtin_amdgcn_global_load_lds(
                    (__attribute__((address_space(1))) void*)(gA + (size_t)(h * 128 + i * 64) * K_DIM + kt * BK),
                    (__attribute__((address_space(3))) void*)(smem + buf * 32768 + h * 16384 + i * 8192 + ldsw),
                    16, 0, 0);
    };
    auto stageB = [&](int buf, int kt) {
        #pragma unroll
        for (int h = 0; h < 2; ++h)
            #pragma unroll
            for (int i = 0; i < 2; ++i)
                __builtin_amdgcn_global_load_lds(
                    (__attribute__((address_space(1))) void*)(gB + (size_t)(h * 128 + i * 64) * K_DIM + kt * BK),
                    (__attribute__((address_space(3))) void*)(smem + 98304 + buf * 32768 + h * 16384 + i * 8192 + ldsw),
                    16, 0, 0);
    };

    // prologue: A(0)->a0, B(0)->b0, A(1)->a1; retire tile0 (oldest 8), keep A(1)
    stageA(0, 0);
    stageB(0, 0);
    stageA(1, 1);
    VMC4();
    BARX();

    int ab = 0, bb = 0;
    #pragma unroll 1
    for (int t = 0; t < 12; ++t) {
        const unsigned short* Ab = lds16 + ab * 16384;
        const unsigned short* Bb = lds16 + 49152 + bb * 16384;
        s16x8 af[4], ag[4], bf[4];

        // ---- p1: (mh=0, ks=0) ----
        #pragma unroll
        for (int ii = 0; ii < 4; ++ii) af[ii] = *(const s16x8*)&Ab[arow[ii] + c0];
        #pragma unroll
        for (int j = 0; j < 4; ++j)  bf[j] = *(const s16x8*)&Bb[brow[j] + c0];
        if (t < 11) stageB(bb ^ 1, t + 1);
        BARX();
        __builtin_amdgcn_s_setprio(1);
        #pragma unroll
        for (int ii = 0; ii < 4; ++ii)
            #pragma unroll
            for (int j = 0; j < 4; ++j)
                acc[ii][j] = __builtin_amdgcn_mfma_f32_16x16x32_bf16(af[ii], bf[j], acc[ii][j], 0, 0, 0);
        __builtin_amdgcn_s_setprio(0);
        BARX();

        // ---- p2: (mh=1, ks=0), reuse bf ----
        #pragma unroll
        for (int ii = 0; ii < 4; ++ii) ag[ii] = *(const s16x8*)&Ab[8192 + arow[ii] + c0];
        if (t < 10) { int a2 = ab ? ab - 1 : 2; stageA(a2, t + 2); }
        BARX();
        __builtin_amdgcn_s_setprio(1);
        #pragma unroll
        for (int ii = 0; ii < 4; ++ii)
            #pragma unroll
            for (int j = 0; j < 4; ++j)
                acc[4 + ii][j] = __builtin_amdgcn_mfma_f32_16x16x32_bf16(ag[ii], bf[j], acc[4 + ii][j], 0, 0, 0);
        __builtin_amdgcn_s_setprio(0);
        BARX();

        // ---- p3: (mh=0, ks=1) ----
        #pragma unroll
        for (int ii = 0; ii < 4; ++ii) af[ii] = *(const s16x8*)&Ab[arow[ii] + c1];
        #pragma unroll
        for (int j = 0; j < 4; ++j)  bf[j] = *(const s16x8*)&Bb[brow[j] + c1];
        BARX();
        __builtin_amdgcn_s_setprio(1);
        #pragma unroll
        for (int ii = 0; ii < 4; ++ii)
            #pragma unroll
            for (int j = 0; j < 4; ++j)
                acc[ii][j] = __builtin_amdgcn_mfma_f32_16x16x32_bf16(af[ii], bf[j], acc[ii][j], 0, 0, 0);
        __builtin_amdgcn_s_setprio(0);
        BARX();

        // ---- p4: (mh=1, ks=1), reuse bf; counted wait for next tile ----
        #pragma unroll
        for (int ii = 0; ii < 4; ++ii) ag[ii] = *(const s16x8*)&Ab[8192 + arow[ii] + c1];
        if (t < 10) { VMC4(); } else { VMC0(); }
        BARX();
        __builtin_amdgcn_s_setprio(1);
        #pragma unroll
        for (int ii = 0; ii < 4; ++ii)
            #pragma unroll
            for (int j = 0; j < 4; ++j)
                acc[4 + ii][j] = __builtin_amdgcn_mfma_f32_16x16x32_bf16(ag[ii], bf[j], acc[4 + ii][j], 0, 0, 0);
        __builtin_amdgcn_s_setprio(0);
        BARX();

        ab = (ab == 2) ? 0 : ab + 1;
        bb ^= 1;
    }

    // Epilogue: slot = nt*4 + wn is wave-local; part[slot][m0+row] = sum over
    // the wave's 64 n-cols of tanh(acc + c[b][n]) * w2[n].  Pad cols: w2=0.
    const int slot = nt * 4 + wn;
    float w2v[4]; int ncj[4];
    #pragma unroll
    for (int j = 0; j < 4; ++j) {
        int nc = n0 + wn * 64 + j * 16 + col;
        ncj[j] = nc;
        w2v[j] = (nc < H1_DIM) ? W21[nc] : (nc < N_REAL ? W22[nc - H1_DIM] : 0.f);
    }
    float* pc = part + (size_t)slot * M_DIM + m0;
    #pragma unroll
    for (int i = 0; i < 8; ++i) {
        #pragma unroll
        for (int r = 0; r < 4; ++r) {
            const int row_local = (i >> 2) * 128 + (i & 3) * 32 + wm * 16 + quad * 4 + r;
            const int b = row_local & (B_DIM - 1);           // m0 % 256 == 0
            float v = 0.f;
            #pragma unroll
            for (int j = 0; j < 4; ++j) {
                float pre = acc[i][j][r] + cbias[b * NPAD + ncj[j]];
                float ex  = __expf(2.f * pre);               // tanh(x)=1-2/(e^{2x}+1)
                float th  = 1.f - 2.f * __builtin_amdgcn_rcpf(ex + 1.f);
                v = fmaf(th, w2v[j], v);
            }
            v += __shfl_xor(v, 1);    // reduce the 16 cols (same quad = same row)
            v += __shfl_xor(v, 2);
            v += __shfl_xor(v, 4);
            v += __shfl_xor(v, 8);
            if (col == 0) pc[row_local] = v;
        }
    }
}

// --- softmax over S per (b, half) from 24 slot-partials; wsum[b][s] = w1+w2 ---
// part layout is [slot][m] with m = s*64 + b; pad slots 22,23 are exact zeros.
__global__ __launch_bounds__(512) void softmax_kernel(const float* __restrict__ part,
                                                      float* __restrict__ wsum) {
    const int b = blockIdx.x, s = threadIdx.x;   // 512 threads = 512 s
    __shared__ float redm[16], reds[16];
    const size_t off = (size_t)s * 64 + b;
    float v0 = 0.f, v1 = 0.f;
    #pragma unroll
    for (int sl = 0; sl < 12; ++sl)       v0 += part[(size_t)sl * M_DIM + off];
    #pragma unroll
    for (int sl = 12; sl < NSLOT; ++sl)   v1 += part[(size_t)sl * M_DIM + off];
    float m0 = v0, m1 = v1;
    #pragma unroll
    for (int offx = 32; offx > 0; offx >>= 1) {
        m0 = fmaxf(m0, __shfl_xor(m0, offx));
        m1 = fmaxf(m1, __shfl_xor(m1, offx));
    }
    const int w = s >> 6;
    if ((s & 63) == 0) { redm[w] = m0; redm[8 + w] = m1; }
    __syncthreads();
    m0 = redm[0]; m1 = redm[8];
    #pragma unroll
    for (int i = 1; i < 8; ++i) { m0 = fmaxf(m0, redm[i]); m1 = fmaxf(m1, redm[8 + i]); }
    float e0 = expf(v0 - m0), e1 = expf(v1 - m1);
    float s0 = e0, s1 = e1;
    #pragma unroll
    for (int offx = 32; offx > 0; offx >>= 1) {
        s0 += __shfl_xor(s0, offx);
        s1 += __shfl_xor(s1, offx);
    }
    if ((s & 63) == 0) { reds[w] = s0; reds[8 + w] = s1; }
    __syncthreads();
    s0 = reds[0]; s1 = reds[8];
    #pragma unroll
    for (int i = 1; i < 8; ++i) { s0 += reds[i]; s1 += reds[8 + i]; }
    wsum[b * S_DIM + s] = e0 / s0 + e1 / s1;
}

// --- out[b,t] += (0.5/S) * sum_{s in chunk} wsum[b][s] * Abf[s,b,t] ---
__global__ __launch_bounds__(128) void wmean_kernel(const unsigned short* __restrict__ Abf,
                                                    const float* __restrict__ wsum,
                                                    float* __restrict__ out) {
    const int b  = blockIdx.x;
    const int tp = blockIdx.y * 128 + threadIdx.x;   // t-pair index 0..383
    const int s0 = blockIdx.z * 128;
    const unsigned short* base = Abf + (size_t)b * T_DIM + tp * 2;
    const float* wp = wsum + b * S_DIM;
    float a0 = 0.f, a1 = 0.f, c0 = 0.f, c1 = 0.f;
    #pragma unroll 4
    for (int s = s0; s < s0 + 128; s += 2) {
        float w0 = wp[s], w1 = wp[s + 1];
        unsigned u0 = *(const unsigned*)(base + (size_t)s * (B_DIM * T_DIM));
        unsigned u1 = *(const unsigned*)(base + (size_t)(s + 1) * (B_DIM * T_DIM));
        a0 = fmaf(w0, __uint_as_float(u0 << 16),          a0);
        a1 = fmaf(w0, __uint_as_float(u0 & 0xffff0000u),  a1);
        c0 = fmaf(w1, __uint_as_float(u1 << 16),          c0);
        c1 = fmaf(w1, __uint_as_float(u1 & 0xffff0000u),  c1);
    }
    atomicAdd(&out[b * T_DIM + tp * 2],     (a0 + c0) * (0.5f / (float)S_DIM));
    atomicAdd(&out[b * T_DIM + tp * 2 + 1], (a1 + c1) * (0.5f / (float)S_DIM));
}

extern "C" void kernel_launch(void* const* d_in, const int* in_sizes, int n_in,
                              void* d_out, int out_size, void* d_ws, size_t ws_size,
                              hipStream_t stream) {
    const float* text = (const float*)d_in[0];
    const float* anp  = (const float*)d_in[1];
    const float* ts   = (const float*)d_in[2];
    const float* W11  = (const float*)d_in[3];
    const float* b11  = (const float*)d_in[4];
    const float* W21  = (const float*)d_in[5];
    // d_in[6] = b21: unused, softmax is shift-invariant
    const float* W12  = (const float*)d_in[7];
    const float* b12  = (const float*)d_in[8];
    const float* W22  = (const float*)d_in[9];
    // d_in[10] = b22: unused
    float* out = (float*)d_out;

    // workspace layout (bytes): total ~56.4 MB
    char* ws = (char*)d_ws;
    unsigned short* Abf = (unsigned short*)ws;                 // 50331648
    unsigned short* Bt  = (unsigned short*)(ws + 50331648);    //  2359296 (1536x768 bf16)
    float* cbias = (float*)(ws + 52690944);                    //   393216 (64x1536 f32)
    float* part  = (float*)(ws + 53084160);                    //  3145728 (24x32768 f32)
    float* wsum  = (float*)(ws + 56229888);                    //   131072

    static int lds_attr_set = 0;
    if (!lds_attr_set) {
        hipFuncSetAttribute((const void*)gemm_score_kernel,
                            hipFuncAttributeMaxDynamicSharedMemorySize, GEMM_LDS);
        lds_attr_set = 1;
    }

    hipMemsetAsync(out, 0, B_DIM * T_DIM * sizeof(float), stream);
    prep_kernel<<<BIAS_BLKS + CONVW_BLKS + CONVA_BLKS, 256, 0, stream>>>(
        ts, text, anp, W11, b11, W12, b12, Abf, Bt, cbias);
    gemm_score_kernel<<<(M_DIM / BM) * (NPAD / BN), 512, GEMM_LDS, stream>>>(
        Abf, Bt, cbias, W21, W22, part);
    softmax_kernel<<<B_DIM, 512, 0, stream>>>(part, wsum);
    wmean_kernel<<<dim3(B_DIM, 3, 4), 128, 0, stream>>>(Abf, wsum, out);
}